// Round 10
// baseline (240.403 us; speedup 1.0000x reference)
//
#include <hip/hip_runtime.h>
#include <hip/hip_bf16.h>

#define S_LEN 2048
#define NHEAD 12
#define NBH 48          // B*H
#define DMODEL 768
#define BR 128          // q rows per block (4 qw x 2 kh waves) — R7-proven
#define BC 128          // keys per K-tile — R7-proven
#define NIT (S_LEN / BC)

typedef __bf16 bf16x8 __attribute__((ext_vector_type(8)));
typedef float f32x4  __attribute__((ext_vector_type(4)));
typedef float f32x16 __attribute__((ext_vector_type(16)));

union B8U { uint4 u; bf16x8 b; };

__device__ __forceinline__ unsigned bf16rne(float f) {
  unsigned u = __float_as_uint(f);
  return (u + 0x7fffu + ((u >> 16) & 1u)) >> 16;
}

// ================= Kernel 1: per-head QKV projection (MFMA) =================
// R8 barrier-free structure (1 barrier total); in-register f32->bf16 W
// conversion (no w_cvt dispatch). Unchanged (rest ~88 us stable).
__global__ __launch_bounds__(256)
void qkv_proj(const float* __restrict__ seq,
              const float* __restrict__ Wq, const float* __restrict__ Wk,
              const float* __restrict__ Wv,
              const float* __restrict__ bq, const float* __restrict__ bk,
              const float* __restrict__ bv,
              unsigned short* __restrict__ Qp, unsigned short* __restrict__ Kp,
              unsigned short* __restrict__ VTp) {
  __shared__ __align__(16) unsigned short xs[128][72];   // 18432 B

  const int tid  = threadIdx.x;
  const int lane = tid & 63;
  const int wave = tid >> 6;
  const int L    = lane >> 5;
  const int l31  = lane & 31;
  const int bh    = blockIdx.x % NBH;    // XCD pin matches flash (id%8 == bh%8)
  const int stile = blockIdx.x / NBH;    // 0..15
  const int b = bh / NHEAD, h = bh % NHEAD;
  const int s0 = stile * 128;

  // ---- stage x tile [128][64] fp32 -> bf16(RNE) LDS, coalesced ----
#pragma unroll
  for (int p = 0; p < 8; ++p) {
    int f = tid + p * 256;
    int row = f >> 4, c4 = f & 15;
    float4 x = *(const float4*)&seq[((size_t)(b * S_LEN + s0 + row)) * DMODEL + h * 64 + c4 * 4];
    uint2 d;
    d.x = bf16rne(x.x) | (bf16rne(x.y) << 16);
    d.y = bf16rne(x.z) | (bf16rne(x.w) << 16);
    *(uint2*)&xs[row][c4 * 4] = d;
  }
  __syncthreads();                       // the ONLY barrier

  bf16x8 af[4];
#pragma unroll
  for (int ks = 0; ks < 4; ++ks)
    af[ks] = *(const bf16x8*)&xs[wave * 32 + l31][ks * 16 + L * 8];

  // per-wave private slice of xs (rows [32*wave, 32*wave+32) = 4608 B)
  unsigned short (*Rt)[72] = (unsigned short(*)[72])(&xs[wave * 32][0]); // [32][72]
  unsigned short (*Vt)[36] = (unsigned short(*)[36])(&xs[wave * 32][0]); // [64][36]

  const float qs = 0.18033688011112042f; // log2(e)/8 (exp2-domain softmax)

  auto wfrag = [&](const float* Wm, int e, int ks) -> bf16x8 {
    const float4* wp = (const float4*)&Wm[((size_t)(h * 64 + e)) * 64 + ks * 16 + L * 8];
    float4 w0 = wp[0], w1 = wp[1];
    B8U t;
    t.u.x = bf16rne(w0.x) | (bf16rne(w0.y) << 16);
    t.u.y = bf16rne(w0.z) | (bf16rne(w0.w) << 16);
    t.u.z = bf16rne(w1.x) | (bf16rne(w1.y) << 16);
    t.u.w = bf16rne(w1.z) | (bf16rne(w1.w) << 16);
    return t.b;
  };

  // ---- Q then K: acc C[e][s] -> bias/scale -> Rt[s][e] -> coalesced stores --
#pragma unroll
  for (int mat = 0; mat < 2; ++mat) {
    const float* Wm  = (mat == 0) ? Wq : Wk;
    const float* bp0 = (mat == 0) ? bq : bk;
    const float sc = (mat == 0) ? qs : 1.0f;
    f32x16 acc[2];
#pragma unroll
    for (int nt = 0; nt < 2; ++nt) {
      const int e = nt * 32 + l31;
      bf16x8 wf[4];
#pragma unroll
      for (int i = 0; i < 16; ++i) acc[nt][i] = 0.f;
#pragma unroll
      for (int ks = 0; ks < 4; ++ks) wf[ks] = wfrag(Wm, e, ks);
#pragma unroll
      for (int ks = 0; ks < 4; ++ks)
        acc[nt] = __builtin_amdgcn_mfma_f32_32x32x16_bf16(wf[ks], af[ks], acc[nt], 0, 0, 0);
    }
#pragma unroll
    for (int nt = 0; nt < 2; ++nt)
#pragma unroll
      for (int rq = 0; rq < 4; ++rq) {
        int e0 = nt * 32 + 8 * rq + 4 * L;
        const float* bp = bp0 + h * 64 + e0;
        ushort4 pv;
        pv.x = (unsigned short)bf16rne((acc[nt][4 * rq + 0] + bp[0]) * sc);
        pv.y = (unsigned short)bf16rne((acc[nt][4 * rq + 1] + bp[1]) * sc);
        pv.z = (unsigned short)bf16rne((acc[nt][4 * rq + 2] + bp[2]) * sc);
        pv.w = (unsigned short)bf16rne((acc[nt][4 * rq + 3] + bp[3]) * sc);
        *(ushort4*)&Rt[l31][e0] = pv;
      }
    unsigned short* P = (mat == 0) ? Qp : Kp;
#pragma unroll
    for (int p = 0; p < 4; ++p) {
      int f = lane + p * 64;             // 256 x 16B chunks = 4 KB wave tile
      int row = f >> 3, c = f & 7;
      uint4 d = *(const uint4*)&Rt[row][c * 8];
      *(uint4*)&P[((size_t)bh * S_LEN + s0 + wave * 32 + row) * 64 + c * 8] = d;
    }
  }

  // ---- V: acc C[s][e] -> bias -> Vt[e][s] -> coalesced stores ----
  {
    f32x16 vacc[2];
#pragma unroll
    for (int nt = 0; nt < 2; ++nt) {
      const int e = nt * 32 + l31;
      bf16x8 wf[4];
#pragma unroll
      for (int i = 0; i < 16; ++i) vacc[nt][i] = 0.f;
#pragma unroll
      for (int ks = 0; ks < 4; ++ks) wf[ks] = wfrag(Wv, e, ks);
#pragma unroll
      for (int ks = 0; ks < 4; ++ks)
        vacc[nt] = __builtin_amdgcn_mfma_f32_32x32x16_bf16(af[ks], wf[ks], vacc[nt], 0, 0, 0);
    }
#pragma unroll
    for (int nt = 0; nt < 2; ++nt) {
      const int e = nt * 32 + l31;
      float bias = bv[h * 64 + e];
#pragma unroll
      for (int rq = 0; rq < 4; ++rq) {
        ushort4 pv;
        pv.x = (unsigned short)bf16rne(vacc[nt][4 * rq + 0] + bias);
        pv.y = (unsigned short)bf16rne(vacc[nt][4 * rq + 1] + bias);
        pv.z = (unsigned short)bf16rne(vacc[nt][4 * rq + 2] + bias);
        pv.w = (unsigned short)bf16rne(vacc[nt][4 * rq + 3] + bias);
        *(ushort4*)&Vt[e][8 * rq + 4 * L] = pv;
      }
    }
#pragma unroll
    for (int p = 0; p < 4; ++p) {
      int f = lane + p * 64;
      int row = f >> 2, c = f & 3;       // row = e 0..63, c*8 = s_local
      uint4 d = *(const uint4*)&Vt[row][c * 8];
      *(uint4*)&VTp[((size_t)bh * 64 + row) * S_LEN + s0 + wave * 32 + c * 8] = d;
    }
  }
}

// lgkm-only barrier: orders LDS ops without draining vmem. Used ONLY for the
// mid-iter Ks read->overwrite hazard (no vmem dependency there).
__device__ __forceinline__ void lds_barrier() {
  __builtin_amdgcn_sched_barrier(0);
  asm volatile("s_waitcnt lgkmcnt(0)" ::: "memory");
  __builtin_amdgcn_s_barrier();
  __builtin_amdgcn_sched_barrier(0);
}

// ============ Kernel 2: flash attention, fixed-base softmax ============
// R13 = R12 with ONE change: the end-of-iter barrier is a full __syncthreads
// again. R12 proved 3 blocks/CU works (occupancy 62%) but its zero-drain
// barriers let co-resident blocks DRIFT in K-tile phase -> L2 reuse collapsed
// (FETCH 27.6 -> 371 MB). The champion's per-iter vmcnt(0) drain is the L2
// alignment mechanism (all blocks of a bh stream the same K-tile window).
// This keeps: single-K + dbuf-V (53248 B -> 3 blocks/CU, one round), cheap
// lgkm-only mid barrier for the K overwrite, drained end barrier for convoy.
__global__ __launch_bounds__(512, 6)
void flash_attn(const unsigned short* __restrict__ Qp,
                const unsigned short* __restrict__ Kp,
                const unsigned short* __restrict__ VTp,
                float* __restrict__ out) {
  __shared__ __align__(16) char smem[53248];
  unsigned short (*Ks)[72]      = (unsigned short(*)[72])smem;                 // [128][72] 18432
  unsigned short (*Vs)[64][136] = (unsigned short(*)[64][136])(smem + 18432);  // 2x17408

  const int tid  = threadIdx.x;
  const int wave = tid >> 6;
  const int lane = tid & 63;
  const int L    = lane >> 5;
  const int l31  = lane & 31;
  const int qw   = wave & 3;    // q-row group
  const int kh   = wave >> 2;   // key half of each 128-key tile
  // XCD pinning: id%8 == bh%8 -> all 16 q-tiles of a bh share one XCD's L2
  const int bh = blockIdx.x % NBH;
  const int qx = blockIdx.x / NBH;
  const int b = bh / NHEAD, h = bh % NHEAD;
  const int q0 = qx * BR;

  // Q frags (B-operand): lane holds Q[q=l31][d=ks*16+L*8+j]
  bf16x8 qfrag[4];
  {
    const uint4* Qv = (const uint4*)Qp;
#pragma unroll
    for (int ks = 0; ks < 4; ++ks) {
      B8U t;
      t.u = Qv[((size_t)bh * S_LEN + q0 + qw * 32 + l31) * 8 + ks * 2 + L];
      qfrag[ks] = t.b;
    }
  }

  f32x16 oacc[2];
#pragma unroll
  for (int mt = 0; mt < 2; ++mt)
#pragma unroll
    for (int i = 0; i < 16; ++i) oacc[mt][i] = 0.f;
  float l_run = 0.f;

  const uint4* Kv = (const uint4*)Kp  + (size_t)bh * S_LEN * 8;
  const uint4* Vv = (const uint4*)VTp + (size_t)bh * 64 * 256;

  uint4 kd[2], vd[2];
#pragma unroll
  for (int j = 0; j < 2; ++j) {
    int f = tid + j * 512;
    kd[j] = Kv[(size_t)(f >> 3) * 8 + (f & 7)];
    vd[j] = Vv[(size_t)(f >> 4) * 256 + (f & 15)];
  }

  // EPV: exp2 + bf16-truncate pack + PV-MFMA for one 32-key score tile (t =
  // global 32-key slot 0..3). l sums the SAME truncated values so rounding
  // bias cancels in p/l.
  int cur = 0;
  auto EPV = [&](const f32x16& sc, int t) {
    unsigned pk[8];
    float la = 0.f, lb = 0.f;
#pragma unroll
    for (int p = 0; p < 8; ++p) {
      unsigned u0 = __float_as_uint(__builtin_amdgcn_exp2f(sc[2 * p]));
      unsigned u1 = __float_as_uint(__builtin_amdgcn_exp2f(sc[2 * p + 1]));
      unsigned d = __builtin_amdgcn_perm(u1, u0, 0x07060302);  // {hi16(u1),hi16(u0)}
      pk[p] = d;
      la += __uint_as_float(d << 16);
      lb += __uint_as_float(d & 0xffff0000u);
    }
    l_run += la + lb;
#pragma unroll
    for (int mk = 0; mk < 2; ++mk) {
      const int m = 2 * t + mk;
      unsigned a0 = pk[4 * mk + 0], a1 = pk[4 * mk + 1];
      unsigned b0 = pk[4 * mk + 2], b1 = pk[4 * mk + 3];
      asm("v_permlane32_swap_b32 %0, %1" : "+v"(a0), "+v"(b0));
      asm("v_permlane32_swap_b32 %0, %1" : "+v"(a1), "+v"(b1));
      B8U t2;
      t2.u.x = a0; t2.u.y = a1; t2.u.z = b0; t2.u.w = b1;
      __builtin_amdgcn_s_setprio(1);
#pragma unroll
      for (int mt = 0; mt < 2; ++mt) {
        bf16x8 va = *(const bf16x8*)&Vs[cur][mt * 32 + l31][m * 16 + L * 8];
        oacc[mt] = __builtin_amdgcn_mfma_f32_32x32x16_bf16(va, t2.b, oacc[mt], 0, 0, 0);
      }
      __builtin_amdgcn_s_setprio(0);
    }
  };

  // prologue: stage tile 0 (K into single buf, V into buf 0)
#pragma unroll
  for (int j = 0; j < 2; ++j) {
    int f = tid + j * 512;
    *(uint4*)&Ks[f >> 3][(f & 7) * 8]     = kd[j];
    *(uint4*)&Vs[0][f >> 4][(f & 15) * 8] = vd[j];
  }
  __syncthreads();

  for (int i = 0; i < NIT; ++i) {
    if (i + 1 < NIT) {               // issue next-tile loads; compute covers them
      int t0n = (i + 1) * BC;
#pragma unroll
      for (int j = 0; j < 2; ++j) {
        int f = tid + j * 512;
        kd[j] = Kv[(size_t)(t0n + (f >> 3)) * 8 + (f & 7)];
        vd[j] = Vv[(size_t)(f >> 4) * 256 + (t0n >> 3) + (f & 15)];
      }
    }

    // ---- S^T = K·Q^T for this wave's key half (rows kh*64 .. kh*64+63) ----
    f32x16 sacc[2];
#pragma unroll
    for (int tl = 0; tl < 2; ++tl)
#pragma unroll
      for (int j = 0; j < 16; ++j) sacc[tl][j] = 0.f;

    __builtin_amdgcn_s_setprio(1);
#pragma unroll
    for (int ks = 0; ks < 4; ++ks)
#pragma unroll
      for (int tl = 0; tl < 2; ++tl) {
        bf16x8 a = *(const bf16x8*)&Ks[kh * 64 + tl * 32 + l31][ks * 16 + L * 8];
        sacc[tl] = __builtin_amdgcn_mfma_f32_32x32x16_bf16(a, qfrag[ks], sacc[tl], 0, 0, 0);
      }
    __builtin_amdgcn_s_setprio(0);

    lds_barrier();                   // all waves done READING Ks (no vmem drain)

    if (i + 1 < NIT) {               // overwrite K buffer; EPV below covers it
#pragma unroll
      for (int j = 0; j < 2; ++j) {
        int f = tid + j * 512;
        *(uint4*)&Ks[f >> 3][(f & 7) * 8] = kd[j];
      }
    }

    EPV(sacc[0], kh * 2 + 0);        // reads Vs[cur] — stable (dbuf)
    EPV(sacc[1], kh * 2 + 1);

    if (i + 1 < NIT) {               // stage next V tile into the other buffer
#pragma unroll
      for (int j = 0; j < 2; ++j) {
        int f = tid + j * 512;
        *(uint4*)&Vs[cur ^ 1][f >> 4][(f & 15) * 8] = vd[j];
      }
    }
    __syncthreads();                 // DRAINED barrier: restores cross-block
    cur ^= 1;                        // K-tile convoy -> L2-temporal streaming
  }

  l_run += __shfl_xor(l_run, 32, 64);   // q-column's rows split between lane pair

  // ---- merge the two key-half partials (pure sums), then normalize ----
  __syncthreads();                       // smem reused as M
  float* M  = (float*)smem;              // [4 qw][32 q][68 e]  34816 B
  float* Ml = (float*)(smem + 34816);    // [4 qw][32 q] l      512 B
  if (kh == 1) {
    float* Mw = M + qw * (32 * 68);
#pragma unroll
    for (int mt = 0; mt < 2; ++mt)
#pragma unroll
      for (int rq = 0; rq < 4; ++rq) {
        f32x4 v;
        v.x = oacc[mt][4 * rq + 0];
        v.y = oacc[mt][4 * rq + 1];
        v.z = oacc[mt][4 * rq + 2];
        v.w = oacc[mt][4 * rq + 3];
        int e0 = mt * 32 + 8 * rq + 4 * L;
        *(f32x4*)&Mw[l31 * 68 + e0] = v;
      }
    if (lane < 32) Ml[qw * 32 + l31] = l_run;
  }
  __syncthreads();
  if (kh == 0) {
    float* Mw = M + qw * (32 * 68);
#pragma unroll
    for (int mt = 0; mt < 2; ++mt)
#pragma unroll
      for (int rq = 0; rq < 4; ++rq) {
        int e0 = mt * 32 + 8 * rq + 4 * L;
        f32x4 v = *(const f32x4*)&Mw[l31 * 68 + e0];
        oacc[mt][4 * rq + 0] += v.x;
        oacc[mt][4 * rq + 1] += v.y;
        oacc[mt][4 * rq + 2] += v.z;
        oacc[mt][4 * rq + 3] += v.w;
      }
    l_run += Ml[qw * 32 + l31];

    // overwrite own region with normalized O^T (same wave: in-order LDS)
    float inv = 1.0f / l_run;
#pragma unroll
    for (int mt = 0; mt < 2; ++mt)
#pragma unroll
      for (int rq = 0; rq < 4; ++rq) {
        f32x4 v;
        v.x = oacc[mt][4 * rq + 0] * inv;
        v.y = oacc[mt][4 * rq + 1] * inv;
        v.z = oacc[mt][4 * rq + 2] * inv;
        v.w = oacc[mt][4 * rq + 3] * inv;
        int e0 = mt * 32 + 8 * rq + 4 * L;
        *(f32x4*)&Mw[l31 * 68 + e0] = v;
      }
#pragma unroll
    for (int p = 0; p < 8; ++p) {
      int q = (lane >> 4) + 4 * p;
      int e4 = lane & 15;
      float4 t = *(const float4*)&Mw[q * 68 + e4 * 4];
      *(float4*)&out[((size_t)(b * S_LEN + q0 + qw * 32 + q)) * DMODEL + h * 64 + e4 * 4] = t;
    }
  }
}

extern "C" void kernel_launch(void* const* d_in, const int* in_sizes, int n_in,
                              void* d_out, int out_size, void* d_ws, size_t ws_size,
                              hipStream_t stream) {
  const float* seq = (const float*)d_in[0];
  const float* Wq  = (const float*)d_in[1];
  const float* Wk  = (const float*)d_in[2];
  const float* Wv  = (const float*)d_in[3];
  const float* bq  = (const float*)d_in[4];
  const float* bk  = (const float*)d_in[5];
  const float* bv  = (const float*)d_in[6];
  float* out = (float*)d_out;

  const size_t qb = (size_t)NBH * S_LEN * 64 * sizeof(unsigned short); // 12.58 MB each
  unsigned short* Qp  = (unsigned short*)d_ws;
  unsigned short* Kp  = (unsigned short*)((char*)d_ws + qb);
  unsigned short* VTp = (unsigned short*)((char*)d_ws + 2 * qb);

  qkv_proj<<<dim3(16 * NBH), 256, 0, stream>>>(seq, Wq, Wk, Wv, bq, bk, bv, Qp, Kp, VTp);
  flash_attn<<<dim3(16 * NBH), 512, 0, stream>>>(Qp, Kp, VTp, out);
}

// Round 11
// 164.854 us; speedup vs baseline: 1.4583x; 1.4583x over previous
//
#include <hip/hip_runtime.h>
#include <hip/hip_bf16.h>

#define S_LEN 2048
#define NHEAD 12
#define NBH 48          // B*H
#define DMODEL 768
#define BR 128          // q rows per block (4 qw x 2 kh waves) — champion
#define BC 128          // keys per K-tile — champion
#define NIT (S_LEN / BC)

typedef __bf16 bf16x8 __attribute__((ext_vector_type(8)));
typedef float f32x4  __attribute__((ext_vector_type(4)));
typedef float f32x16 __attribute__((ext_vector_type(16)));

union B8U { uint4 u; bf16x8 b; };

__device__ __forceinline__ unsigned bf16rne(float f) {
  unsigned u = __float_as_uint(f);
  return (u + 0x7fffu + ((u >> 16) & 1u)) >> 16;
}

// ================= Kernel 1: per-head QKV projection (MFMA) =================
// Barrier-free after the x-stage (1 barrier total); in-register f32->bf16 W
// conversion (no w_cvt dispatch).
__global__ __launch_bounds__(256)
void qkv_proj(const float* __restrict__ seq,
              const float* __restrict__ Wq, const float* __restrict__ Wk,
              const float* __restrict__ Wv,
              const float* __restrict__ bq, const float* __restrict__ bk,
              const float* __restrict__ bv,
              unsigned short* __restrict__ Qp, unsigned short* __restrict__ Kp,
              unsigned short* __restrict__ VTp) {
  __shared__ __align__(16) unsigned short xs[128][72];   // 18432 B

  const int tid  = threadIdx.x;
  const int lane = tid & 63;
  const int wave = tid >> 6;
  const int L    = lane >> 5;
  const int l31  = lane & 31;
  const int bh    = blockIdx.x % NBH;    // XCD pin matches flash (id%8 == bh%8)
  const int stile = blockIdx.x / NBH;    // 0..15
  const int b = bh / NHEAD, h = bh % NHEAD;
  const int s0 = stile * 128;

  // ---- stage x tile [128][64] fp32 -> bf16(RNE) LDS, coalesced ----
#pragma unroll
  for (int p = 0; p < 8; ++p) {
    int f = tid + p * 256;
    int row = f >> 4, c4 = f & 15;
    float4 x = *(const float4*)&seq[((size_t)(b * S_LEN + s0 + row)) * DMODEL + h * 64 + c4 * 4];
    uint2 d;
    d.x = bf16rne(x.x) | (bf16rne(x.y) << 16);
    d.y = bf16rne(x.z) | (bf16rne(x.w) << 16);
    *(uint2*)&xs[row][c4 * 4] = d;
  }
  __syncthreads();                       // the ONLY barrier

  bf16x8 af[4];
#pragma unroll
  for (int ks = 0; ks < 4; ++ks)
    af[ks] = *(const bf16x8*)&xs[wave * 32 + l31][ks * 16 + L * 8];

  // per-wave private slice of xs (rows [32*wave, 32*wave+32) = 4608 B)
  unsigned short (*Rt)[72] = (unsigned short(*)[72])(&xs[wave * 32][0]); // [32][72]
  unsigned short (*Vt)[36] = (unsigned short(*)[36])(&xs[wave * 32][0]); // [64][36]

  const float qs = 0.18033688011112042f; // log2(e)/8 (exp2-domain softmax)

  auto wfrag = [&](const float* Wm, int e, int ks) -> bf16x8 {
    const float4* wp = (const float4*)&Wm[((size_t)(h * 64 + e)) * 64 + ks * 16 + L * 8];
    float4 w0 = wp[0], w1 = wp[1];
    B8U t;
    t.u.x = bf16rne(w0.x) | (bf16rne(w0.y) << 16);
    t.u.y = bf16rne(w0.z) | (bf16rne(w0.w) << 16);
    t.u.z = bf16rne(w1.x) | (bf16rne(w1.y) << 16);
    t.u.w = bf16rne(w1.z) | (bf16rne(w1.w) << 16);
    return t.b;
  };

  // ---- Q then K: acc C[e][s] -> bias/scale -> Rt[s][e] -> coalesced stores --
#pragma unroll
  for (int mat = 0; mat < 2; ++mat) {
    const float* Wm  = (mat == 0) ? Wq : Wk;
    const float* bp0 = (mat == 0) ? bq : bk;
    const float sc = (mat == 0) ? qs : 1.0f;
    f32x16 acc[2];
#pragma unroll
    for (int nt = 0; nt < 2; ++nt) {
      const int e = nt * 32 + l31;
      bf16x8 wf[4];
#pragma unroll
      for (int i = 0; i < 16; ++i) acc[nt][i] = 0.f;
#pragma unroll
      for (int ks = 0; ks < 4; ++ks) wf[ks] = wfrag(Wm, e, ks);
#pragma unroll
      for (int ks = 0; ks < 4; ++ks)
        acc[nt] = __builtin_amdgcn_mfma_f32_32x32x16_bf16(wf[ks], af[ks], acc[nt], 0, 0, 0);
    }
#pragma unroll
    for (int nt = 0; nt < 2; ++nt)
#pragma unroll
      for (int rq = 0; rq < 4; ++rq) {
        int e0 = nt * 32 + 8 * rq + 4 * L;
        const float* bp = bp0 + h * 64 + e0;
        ushort4 pv;
        pv.x = (unsigned short)bf16rne((acc[nt][4 * rq + 0] + bp[0]) * sc);
        pv.y = (unsigned short)bf16rne((acc[nt][4 * rq + 1] + bp[1]) * sc);
        pv.z = (unsigned short)bf16rne((acc[nt][4 * rq + 2] + bp[2]) * sc);
        pv.w = (unsigned short)bf16rne((acc[nt][4 * rq + 3] + bp[3]) * sc);
        *(ushort4*)&Rt[l31][e0] = pv;
      }
    unsigned short* P = (mat == 0) ? Qp : Kp;
#pragma unroll
    for (int p = 0; p < 4; ++p) {
      int f = lane + p * 64;             // 256 x 16B chunks = 4 KB wave tile
      int row = f >> 3, c = f & 7;
      uint4 d = *(const uint4*)&Rt[row][c * 8];
      *(uint4*)&P[((size_t)bh * S_LEN + s0 + wave * 32 + row) * 64 + c * 8] = d;
    }
  }

  // ---- V: acc C[s][e] -> bias -> Vt[e][s] -> coalesced stores ----
  {
    f32x16 vacc[2];
#pragma unroll
    for (int nt = 0; nt < 2; ++nt) {
      const int e = nt * 32 + l31;
      bf16x8 wf[4];
#pragma unroll
      for (int i = 0; i < 16; ++i) vacc[nt][i] = 0.f;
#pragma unroll
      for (int ks = 0; ks < 4; ++ks) wf[ks] = wfrag(Wv, e, ks);
#pragma unroll
      for (int ks = 0; ks < 4; ++ks)
        vacc[nt] = __builtin_amdgcn_mfma_f32_32x32x16_bf16(af[ks], wf[ks], vacc[nt], 0, 0, 0);
    }
#pragma unroll
    for (int nt = 0; nt < 2; ++nt) {
      const int e = nt * 32 + l31;
      float bias = bv[h * 64 + e];
#pragma unroll
      for (int rq = 0; rq < 4; ++rq) {
        ushort4 pv;
        pv.x = (unsigned short)bf16rne(vacc[nt][4 * rq + 0] + bias);
        pv.y = (unsigned short)bf16rne(vacc[nt][4 * rq + 1] + bias);
        pv.z = (unsigned short)bf16rne(vacc[nt][4 * rq + 2] + bias);
        pv.w = (unsigned short)bf16rne(vacc[nt][4 * rq + 3] + bias);
        *(ushort4*)&Vt[e][8 * rq + 4 * L] = pv;
      }
    }
#pragma unroll
    for (int p = 0; p < 4; ++p) {
      int f = lane + p * 64;
      int row = f >> 2, c = f & 3;       // row = e 0..63, c*8 = s_local
      uint4 d = *(const uint4*)&Vt[row][c * 8];
      *(uint4*)&VTp[((size_t)bh * 64 + row) * S_LEN + s0 + wave * 32 + c * 8] = d;
    }
  }
}

// ============ Kernel 2: flash attention, fixed-base softmax ============
// CHAMPION (Round-4, 70.2 us flash): double-buffered K+V LDS, ONE drained
// barrier per iter, kh-split, 2 blocks/CU. Verbatim revert — every structural
// deviation tried (more waves R6, BC=64 R9, BR=256 R10, K-global R11,
// single-K 3blk R12/R13) regressed via barriers / L2 thrash / VGPR spills.
__global__ __launch_bounds__(512)
void flash_attn(const unsigned short* __restrict__ Qp,
                const unsigned short* __restrict__ Kp,
                const unsigned short* __restrict__ VTp,
                float* __restrict__ out) {
  __shared__ __align__(16) char smem[71680];
  unsigned short (*Ks)[128][72]  = (unsigned short(*)[128][72])smem;            // 2x18432 B
  unsigned short (*Vs)[64][136]  = (unsigned short(*)[64][136])(smem + 36864);  // 2x17408 B

  const int tid  = threadIdx.x;
  const int wave = tid >> 6;
  const int lane = tid & 63;
  const int L    = lane >> 5;
  const int l31  = lane & 31;
  const int qw   = wave & 3;    // q-row group
  const int kh   = wave >> 2;   // key half of each tile
  // XCD pinning: id%8 == bh%8 -> all 16 q-tiles of a bh share one XCD's L2
  const int bh = blockIdx.x % NBH;
  const int qx = blockIdx.x / NBH;
  const int b = bh / NHEAD, h = bh % NHEAD;
  const int q0 = qx * BR;

  // Q frags (B-operand): lane holds Q[q=l31][d=ks*16+L*8+j]
  bf16x8 qfrag[4];
  {
    const uint4* Qv = (const uint4*)Qp;
#pragma unroll
    for (int ks = 0; ks < 4; ++ks) {
      B8U t;
      t.u = Qv[((size_t)bh * S_LEN + q0 + qw * 32 + l31) * 8 + ks * 2 + L];
      qfrag[ks] = t.b;
    }
  }

  f32x16 oacc[2];
#pragma unroll
  for (int mt = 0; mt < 2; ++mt)
#pragma unroll
    for (int i = 0; i < 16; ++i) oacc[mt][i] = 0.f;
  float l_run = 0.f;

  const uint4* Kv = (const uint4*)Kp  + (size_t)bh * S_LEN * 8;
  const uint4* Vv = (const uint4*)VTp + (size_t)bh * 64 * 256;

  uint4 kd[2], vd[2];
#pragma unroll
  for (int j = 0; j < 2; ++j) {
    int f = tid + j * 512;
    kd[j] = Kv[(size_t)(f >> 3) * 8 + (f & 7)];
    vd[j] = Vv[(size_t)(f >> 4) * 256 + (f & 15)];
  }

  // EPV: exp2 + bf16-truncate pack + PV-MFMA for one 32-key score tile (t =
  // global 32-key slot 0..3). l sums the SAME truncated values so rounding
  // bias cancels in p/l.
  int cur = 0;
  auto EPV = [&](const f32x16& sc, int t) {
    unsigned pk[8];
    float la = 0.f, lb = 0.f;
#pragma unroll
    for (int p = 0; p < 8; ++p) {
      unsigned u0 = __float_as_uint(__builtin_amdgcn_exp2f(sc[2 * p]));
      unsigned u1 = __float_as_uint(__builtin_amdgcn_exp2f(sc[2 * p + 1]));
      unsigned d = __builtin_amdgcn_perm(u1, u0, 0x07060302);  // {hi16(u1),hi16(u0)}
      pk[p] = d;
      la += __uint_as_float(d << 16);
      lb += __uint_as_float(d & 0xffff0000u);
    }
    l_run += la + lb;
#pragma unroll
    for (int mk = 0; mk < 2; ++mk) {
      const int m = 2 * t + mk;
      unsigned a0 = pk[4 * mk + 0], a1 = pk[4 * mk + 1];
      unsigned b0 = pk[4 * mk + 2], b1 = pk[4 * mk + 3];
      asm("v_permlane32_swap_b32 %0, %1" : "+v"(a0), "+v"(b0));
      asm("v_permlane32_swap_b32 %0, %1" : "+v"(a1), "+v"(b1));
      B8U t2;
      t2.u.x = a0; t2.u.y = a1; t2.u.z = b0; t2.u.w = b1;
      __builtin_amdgcn_s_setprio(1);
#pragma unroll
      for (int mt = 0; mt < 2; ++mt) {
        bf16x8 va = *(const bf16x8*)&Vs[cur][mt * 32 + l31][m * 16 + L * 8];
        oacc[mt] = __builtin_amdgcn_mfma_f32_32x32x16_bf16(va, t2.b, oacc[mt], 0, 0, 0);
      }
      __builtin_amdgcn_s_setprio(0);
    }
  };

  // prologue: stage tile 0 into buf 0
#pragma unroll
  for (int j = 0; j < 2; ++j) {
    int f = tid + j * 512;
    *(uint4*)&Ks[0][f >> 3][(f & 7) * 8]  = kd[j];
    *(uint4*)&Vs[0][f >> 4][(f & 15) * 8] = vd[j];
  }
  __syncthreads();

  for (int i = 0; i < NIT; ++i) {
    if (i + 1 < NIT) {               // issue next-tile loads; compute covers them
      int t0n = (i + 1) * BC;
#pragma unroll
      for (int j = 0; j < 2; ++j) {
        int f = tid + j * 512;
        kd[j] = Kv[(size_t)(t0n + (f >> 3)) * 8 + (f & 7)];
        vd[j] = Vv[(size_t)(f >> 4) * 256 + (t0n >> 3) + (f & 15)];
      }
    }

    // ---- S^T = K·Q^T for this wave's key half (tiles kh*2, kh*2+1) ----
    f32x16 sacc[2];
#pragma unroll
    for (int tl = 0; tl < 2; ++tl)
#pragma unroll
      for (int j = 0; j < 16; ++j) sacc[tl][j] = 0.f;

    __builtin_amdgcn_s_setprio(1);
#pragma unroll
    for (int ks = 0; ks < 4; ++ks)
#pragma unroll
      for (int tl = 0; tl < 2; ++tl) {
        bf16x8 a = *(const bf16x8*)&Ks[cur][(kh * 2 + tl) * 32 + l31][ks * 16 + L * 8];
        sacc[tl] = __builtin_amdgcn_mfma_f32_32x32x16_bf16(a, qfrag[ks], sacc[tl], 0, 0, 0);
      }
    __builtin_amdgcn_s_setprio(0);

    EPV(sacc[0], kh * 2 + 0);
    EPV(sacc[1], kh * 2 + 1);

    if (i + 1 < NIT) {               // stage next tile into the other buffer
#pragma unroll
      for (int j = 0; j < 2; ++j) {
        int f = tid + j * 512;
        *(uint4*)&Ks[cur ^ 1][f >> 3][(f & 7) * 8]  = kd[j];
        *(uint4*)&Vs[cur ^ 1][f >> 4][(f & 15) * 8] = vd[j];
      }
    }
    __syncthreads();                 // single barrier; nothing outstanding
    cur ^= 1;
  }

  l_run += __shfl_xor(l_run, 32, 64);   // q-column's rows split between lane pair

  // ---- merge the two key-half partials (pure sums), then normalize ----
  float* M  = (float*)smem;              // [4 qw][32 q][68 e]  34816 B
  float* Ml = (float*)(smem + 34816);    // [4 qw][32 q] l      512 B
  if (kh == 1) {
    float* Mw = M + qw * (32 * 68);
#pragma unroll
    for (int mt = 0; mt < 2; ++mt)
#pragma unroll
      for (int rq = 0; rq < 4; ++rq) {
        f32x4 v;
        v.x = oacc[mt][4 * rq + 0];
        v.y = oacc[mt][4 * rq + 1];
        v.z = oacc[mt][4 * rq + 2];
        v.w = oacc[mt][4 * rq + 3];
        int e0 = mt * 32 + 8 * rq + 4 * L;
        *(f32x4*)&Mw[l31 * 68 + e0] = v;
      }
    if (lane < 32) Ml[qw * 32 + l31] = l_run;
  }
  __syncthreads();
  if (kh == 0) {
    float* Mw = M + qw * (32 * 68);
#pragma unroll
    for (int mt = 0; mt < 2; ++mt)
#pragma unroll
      for (int rq = 0; rq < 4; ++rq) {
        int e0 = mt * 32 + 8 * rq + 4 * L;
        f32x4 v = *(const f32x4*)&Mw[l31 * 68 + e0];
        oacc[mt][4 * rq + 0] += v.x;
        oacc[mt][4 * rq + 1] += v.y;
        oacc[mt][4 * rq + 2] += v.z;
        oacc[mt][4 * rq + 3] += v.w;
      }
    l_run += Ml[qw * 32 + l31];
  }
  __syncthreads();                       // M dead before Os reuse

  if (kh == 0) {
    float* Os = (float*)smem + qw * (32 * 68);
    float inv = 1.0f / l_run;
#pragma unroll
    for (int mt = 0; mt < 2; ++mt)
#pragma unroll
      for (int rq = 0; rq < 4; ++rq) {
        f32x4 v;
        v.x = oacc[mt][4 * rq + 0] * inv;
        v.y = oacc[mt][4 * rq + 1] * inv;
        v.z = oacc[mt][4 * rq + 2] * inv;
        v.w = oacc[mt][4 * rq + 3] * inv;
        int e0 = mt * 32 + 8 * rq + 4 * L;
        *(f32x4*)&Os[l31 * 68 + e0] = v;
      }
#pragma unroll
    for (int p = 0; p < 8; ++p) {
      int q = (lane >> 4) + 4 * p;
      int e4 = lane & 15;
      float4 t = *(const float4*)&Os[q * 68 + e4 * 4];
      *(float4*)&out[((size_t)(b * S_LEN + q0 + qw * 32 + q)) * DMODEL + h * 64 + e4 * 4] = t;
    }
  }
}

extern "C" void kernel_launch(void* const* d_in, const int* in_sizes, int n_in,
                              void* d_out, int out_size, void* d_ws, size_t ws_size,
                              hipStream_t stream) {
  const float* seq = (const float*)d_in[0];
  const float* Wq  = (const float*)d_in[1];
  const float* Wk  = (const float*)d_in[2];
  const float* Wv  = (const float*)d_in[3];
  const float* bq  = (const float*)d_in[4];
  const float* bk  = (const float*)d_in[5];
  const float* bv  = (const float*)d_in[6];
  float* out = (float*)d_out;

  const size_t qb = (size_t)NBH * S_LEN * 64 * sizeof(unsigned short); // 12.58 MB each
  unsigned short* Qp  = (unsigned short*)d_ws;
  unsigned short* Kp  = (unsigned short*)((char*)d_ws + qb);
  unsigned short* VTp = (unsigned short*)((char*)d_ws + 2 * qb);

  qkv_proj<<<dim3(16 * NBH), 256, 0, stream>>>(seq, Wq, Wk, Wv, bq, bk, bv, Qp, Kp, VTp);
  flash_attn<<<dim3(16 * NBH), 512, 0, stream>>>(Qp, Kp, VTp, out);
}